// Round 3
// baseline (69.893 us; speedup 1.0000x reference)
//
#include <hip/hip_runtime.h>
#include <hip/hip_bf16.h>

// ============================================================================
// Exact algebra (verified rounds 1-2): pos branch is rank-1 in the query index
// => pos_attn rows identical = w[b,h,j] = softmax_j(-s[b,h,j]); renorm no-op.
// out_head = (1-g)*softmax(QK^T/sqrt(dh))@V + g*(w@V).
// bf16 MFMA 32x32x16; C/D: col=lane&31, row=(reg&3)+8*(reg>>2)+4*(lane>>5).
// No-max softmax: logits pre-scaled to exp2 units, sigma~1.44 => exp2 safe.
// ============================================================================

constexpr int N_ = 1024, PD_ = 16;

typedef short  s8v  __attribute__((ext_vector_type(8)));
typedef float  f16v __attribute__((ext_vector_type(16)));
typedef unsigned u4v __attribute__((ext_vector_type(4)));

__device__ inline unsigned pkbf(float lo, float hi) {
  unsigned r;
  asm("v_cvt_pk_bf16_f32 %0, %1, %2" : "=v"(r) : "v"(lo), "v"(hi));
  return r;
}
__device__ inline short bf16r(float f) {
  unsigned u = __float_as_uint(f);
  u += 0x7fff + ((u >> 16) & 1);
  return (short)(u >> 16);
}
__device__ inline float bfu(short s) {
  return __uint_as_float(((unsigned)(unsigned short)s) << 16);
}

// ---------------- K1: W^T->bf16 (64 blocks) + pos MLP+softmax (32 blocks) ---
__global__ __launch_bounds__(256) void k_prep(
    const float* __restrict__ Wq, const float* __restrict__ Wk,
    const float* __restrict__ Wv, const float* __restrict__ Wo,
    const float* __restrict__ pos, const float* __restrict__ Wp1,
    const float* __restrict__ bp1, const float* __restrict__ Wp2,
    const float* __restrict__ bp2, const float* __restrict__ Wh,
    short* __restrict__ Wt, short* __restrict__ Wot, float* __restrict__ Ww)
{
  __shared__ float tile[64][65];
  __shared__ float sWp1[256], sbp1[16], sWp2[512], sbp2[32], sWhc[32];
  __shared__ float redm[4], reds[4];
  int bid = blockIdx.x;
  int tid = threadIdx.x;

  if (bid < 64) {
    // ---- W transpose + bf16 (Wq pre-scaled by log2(e)/sqrt(32)) ----
    int mat = bid >> 4, t = bid & 15;
    int k0 = (t >> 2) * 64, c0 = (t & 3) * 64;
    const float* W = mat == 0 ? Wq : mat == 1 ? Wk : mat == 2 ? Wv : Wo;
    float scale = (mat == 0) ? 0.2550348662f : 1.0f;
#pragma unroll
    for (int i = 0; i < 16; ++i) {
      int e = tid + i * 256;
      int kr = e >> 6, cc = e & 63;
      tile[kr][cc] = W[(size_t)(k0 + kr) * 256 + c0 + cc];
    }
    __syncthreads();
    short* dst = (mat == 3) ? Wot : (Wt + mat * 65536);
#pragma unroll
    for (int i = 0; i < 16; ++i) {
      int e = tid + i * 256;
      int cr = e >> 6, kk = e & 63;
      dst[(size_t)(c0 + cr) * 256 + k0 + kk] = bf16r(tile[kk][cr] * scale);
    }
    return;
  }

  // ---- pos branch: one block per (b,h); thread handles 4 n's ----
  int bh = bid - 64;
  int b = bh >> 3, h = bh & 7;
  sWp1[tid] = Wp1[tid];
  sWp2[tid] = Wp2[tid];
  sWp2[tid + 256] = Wp2[tid + 256];
  if (tid < 16) sbp1[tid] = bp1[tid];
  if (tid < 32) { sbp2[tid] = bp2[tid]; sWhc[tid] = Wh[tid * 8 + h]; }
  __syncthreads();

  float a[4];
#pragma unroll
  for (int nn = 0; nn < 4; ++nn) {
    int n = nn * 256 + tid;
    const float* prow = pos + (size_t)((b << 10) + n) * PD_;
    float pr[16];
#pragma unroll
    for (int r = 0; r < 16; ++r) pr[r] = prow[r];
    float h1[16];
#pragma unroll
    for (int c = 0; c < 16; ++c) {
      float v = sbp1[c];
#pragma unroll
      for (int r = 0; r < 16; ++r) v = fmaf(pr[r], sWp1[r * 16 + c], v);
      h1[c] = fmaxf(v, 0.0f);
    }
    float s = 0.0f;
#pragma unroll
    for (int d = 0; d < 32; ++d) {
      float v = sbp2[d];
#pragma unroll
      for (int c = 0; c < 16; ++c) v = fmaf(h1[c], sWp2[c * 32 + d], v);
      s = fmaf(v, sWhc[d], s);
    }
    a[nn] = -s;   // bh[h] constant over n: cancels
  }
  float m = fmaxf(fmaxf(a[0], a[1]), fmaxf(a[2], a[3]));
#pragma unroll
  for (int off = 32; off >= 1; off >>= 1) m = fmaxf(m, __shfl_xor(m, off));
  if ((tid & 63) == 0) redm[tid >> 6] = m;
  __syncthreads();
  float M = fmaxf(fmaxf(redm[0], redm[1]), fmaxf(redm[2], redm[3]));
  float e0 = __expf(a[0] - M), e1 = __expf(a[1] - M);
  float e2 = __expf(a[2] - M), e3 = __expf(a[3] - M);
  float su = e0 + e1 + e2 + e3;
#pragma unroll
  for (int off = 32; off >= 1; off >>= 1) su += __shfl_xor(su, off);
  if ((tid & 63) == 0) reds[tid >> 6] = su;
  __syncthreads();
  float inv = 1.0f / (reds[0] + reds[1] + reds[2] + reds[3]);
  float* wr = Ww + (size_t)bh * N_;
  wr[tid]        = e0 * inv;
  wr[tid + 256]  = e1 * inv;
  wr[tid + 512]  = e2 * inv;
  wr[tid + 768]  = e3 * inv;
}

// ---------------- K2: QKV GEMM (f32 x inline-packed), 32x32/wave ------------
__global__ __launch_bounds__(256) void k_qkv(
    const float* __restrict__ x, const short* __restrict__ Wt,
    short* __restrict__ Qb, short* __restrict__ Kb, short* __restrict__ Vtb)
{
  int tid = threadIdx.x;
  int w = tid >> 6, l = tid & 63, H = l >> 5, li = l & 31;
  int bid = blockIdx.x;
  int cb = bid % 12, mb = bid / 12;
  int m0 = mb * 64 + (w & 1) * 32;
  int c0 = cb * 64 + (w >> 1) * 32;
  const float* Ap = x + (size_t)(m0 + li) * 256 + 8 * H;
  const short* Bp = Wt + (size_t)(c0 + li) * 256 + 8 * H;
  f16v acc = {};
#pragma unroll
  for (int kc = 0; kc < 16; ++kc) {
    float4 a0 = *(const float4*)(Ap + 16 * kc);
    float4 a1 = *(const float4*)(Ap + 16 * kc + 4);
    u4v ua = { pkbf(a0.x, a0.y), pkbf(a0.z, a0.w), pkbf(a1.x, a1.y), pkbf(a1.z, a1.w) };
    s8v bf = *(const s8v*)(Bp + 16 * kc);
    acc = __builtin_amdgcn_mfma_f32_32x32x16_bf16(__builtin_bit_cast(s8v, ua), bf, acc, 0, 0, 0);
  }
  int mat = c0 >> 8, mc = c0 & 255;
  int h = mc >> 5;
  int b = m0 >> 10, nb = m0 & 1023;
  int bh = b * 8 + h;
  if (mat < 2) {
    short* Dst = (mat == 0) ? Qb : Kb;
#pragma unroll
    for (int r = 0; r < 16; ++r) {
      int crow = (r & 3) + 8 * (r >> 2) + 4 * H;
      Dst[((size_t)(bh * 1024 + nb + crow)) * 32 + li] = bf16r(acc[r]);
    }
  } else {
#pragma unroll
    for (int q2 = 0; q2 < 4; ++q2) {
      uint2 val = make_uint2(pkbf(acc[q2 * 4 + 0], acc[q2 * 4 + 1]),
                             pkbf(acc[q2 * 4 + 2], acc[q2 * 4 + 3]));
      *(uint2*)(Vtb + ((size_t)(bh * 32 + li)) * 1024 + nb + 8 * q2 + 4 * H) = val;
    }
  }
}

// ---------------- K3: flash attn (no-max exp2) + fused pv, split-bf16 OH ----
__global__ __launch_bounds__(256) void k_attn(
    const short* __restrict__ Qb, const short* __restrict__ Kb,
    const short* __restrict__ Vtb, const float* __restrict__ Ww,
    const float* __restrict__ gate,
    short* __restrict__ OHhi, short* __restrict__ OHlo)
{
  __shared__ float sw[1024];
  __shared__ float sml[4][32];
  __shared__ float sO[4][32][33];
  __shared__ float sPv[8][33];
  int tid = threadIdx.x;
  int w = tid >> 6, l = tid & 63, H = l >> 5, li = l & 31;
  int bid = blockIdx.x;
  int bh = (bid & 7) * 4 + (bid >> 8);   // 4 bh per XCD -> K/V L2-resident
  int qb = (bid >> 3) & 31;
  int n0 = qb * 32;

  *(float4*)(sw + tid * 4) = *(const float4*)(Ww + (size_t)bh * N_ + tid * 4);

  const short* Qp = Qb + ((size_t)(bh * 1024 + n0 + li)) * 32 + 8 * H;
  s8v qf0 = *(const s8v*)(Qp);
  s8v qf1 = *(const s8v*)(Qp + 16);
  const short* Kbase = Kb + ((size_t)(bh * 1024)) * 32 + 8 * H;
  const short* Vbase = Vtb + ((size_t)(bh * 32 + li)) * 1024 + 8 * H;

  f16v acc = {};
  float lsum = 0.0f;

  for (int ch = 0; ch < 8; ++ch) {
    int jb = w * 256 + ch * 32;
    const short* Kp = Kbase + (size_t)(jb + li) * 32;
    s8v kf0 = *(const s8v*)(Kp);
    s8v kf1 = *(const s8v*)(Kp + 16);
    const short* Vp = Vbase + jb;
    s8v vf0 = *(const s8v*)(Vp);
    s8v vf1 = *(const s8v*)(Vp + 16);

    f16v S = {};
    S = __builtin_amdgcn_mfma_f32_32x32x16_bf16(kf0, qf0, S, 0, 0, 0);
    S = __builtin_amdgcn_mfma_f32_32x32x16_bf16(kf1, qf1, S, 0, 0, 0);

    float p[16];
#pragma unroll
    for (int r = 0; r < 16; ++r) {
      p[r] = __builtin_amdgcn_exp2f(S[r]);   // no max: sigma(S)~1.44, safe
      lsum += p[r];
    }

    unsigned a0 = pkbf(p[0], p[1]),  a1 = pkbf(p[2], p[3]);
    unsigned b0 = pkbf(p[4], p[5]),  b1 = pkbf(p[6], p[7]);
    unsigned c0 = pkbf(p[8], p[9]),  c1 = pkbf(p[10], p[11]);
    unsigned d0 = pkbf(p[12], p[13]), d1 = pkbf(p[14], p[15]);
    unsigned sa0 = __shfl_xor(a0, 32), sa1 = __shfl_xor(a1, 32);
    unsigned sb0 = __shfl_xor(b0, 32), sb1 = __shfl_xor(b1, 32);
    unsigned sc0 = __shfl_xor(c0, 32), sc1 = __shfl_xor(c1, 32);
    unsigned sd0 = __shfl_xor(d0, 32), sd1 = __shfl_xor(d1, 32);
    u4v t0 = { H ? sb0 : a0, H ? sb1 : a1, H ? b0 : sa0, H ? b1 : sa1 };
    u4v t1 = { H ? sd0 : c0, H ? sd1 : c1, H ? d0 : sc0, H ? d1 : sc1 };

    acc = __builtin_amdgcn_mfma_f32_32x32x16_bf16(vf0, __builtin_bit_cast(s8v, t0), acc, 0, 0, 0);
    acc = __builtin_amdgcn_mfma_f32_32x32x16_bf16(vf1, __builtin_bit_cast(s8v, t1), acc, 0, 0, 0);
  }

  lsum += __shfl_xor(lsum, 32);
  if (H == 0) sml[w][li] = lsum;
#pragma unroll
  for (int r = 0; r < 16; ++r) {
    int d = (r & 3) + 8 * (r >> 2) + 4 * H;
    sO[w][d][li] = acc[r];
  }
  __syncthreads();

  // pv partial: thread -> (d = tid&31, key segment = tid>>5)
  {
    int d = tid & 31, seg = tid >> 5;
    const short* Vp = Vtb + ((size_t)(bh * 32 + d)) * 1024 + seg * 128;
    const float* wp = sw + seg * 128;
    float s = 0.0f;
    for (int nn = 0; nn < 128; nn += 8) {
      s8v v = *(const s8v*)(Vp + nn);
#pragma unroll
      for (int j = 0; j < 8; ++j) s = fmaf(wp[nn + j], bfu(v[j]), s);
    }
    sPv[seg][d] = s;
  }
  __syncthreads();

  // combine 4 wave-partials + gate, write split-bf16 OH
  int i = tid >> 3, dq = (tid & 7) * 4;
  float L = sml[0][i] + sml[1][i] + sml[2][i] + sml[3][i];
  int b = bh >> 3, h = bh & 7;
  float gh = 1.0f / (1.0f + __expf(-gate[h]));
  float invL = (1.0f - gh) / L;
  float o[4];
#pragma unroll
  for (int q = 0; q < 4; ++q) {
    float pv = sPv[0][dq + q] + sPv[1][dq + q] + sPv[2][dq + q] + sPv[3][dq + q]
             + sPv[4][dq + q] + sPv[5][dq + q] + sPv[6][dq + q] + sPv[7][dq + q];
    o[q] = (sO[0][dq + q][i] + sO[1][dq + q][i] + sO[2][dq + q][i] + sO[3][dq + q][i]) * invL
         + gh * pv;
  }
  float hi[4], lo[4];
#pragma unroll
  for (int q = 0; q < 4; ++q) {
    hi[q] = bfu(bf16r(o[q]));
    lo[q] = o[q] - hi[q];
  }
  size_t off = ((size_t)(b * 1024 + n0 + i)) * 256 + h * 32 + dq;
  *(uint2*)(OHhi + off) = make_uint2(pkbf(hi[0], hi[1]), pkbf(hi[2], hi[3]));
  *(uint2*)(OHlo + off) = make_uint2(pkbf(lo[0], lo[1]), pkbf(lo[2], lo[3]));
}

// ---------------- K4: out = (OHhi+OHlo) @ Wo + bo ---------------------------
__global__ __launch_bounds__(256) void k_out(
    const short* __restrict__ OHhi, const short* __restrict__ OHlo,
    const short* __restrict__ Wot, const float* __restrict__ bo,
    float* __restrict__ out)
{
  int tid = threadIdx.x;
  int w = tid >> 6, l = tid & 63, H = l >> 5, li = l & 31;
  int bid = blockIdx.x;
  int m0 = (bid >> 2) * 64 + (w & 1) * 32;
  int c0 = (bid & 3) * 64 + (w >> 1) * 32;
  const short* Ah = OHhi + (size_t)(m0 + li) * 256 + 8 * H;
  const short* Al = OHlo + (size_t)(m0 + li) * 256 + 8 * H;
  const short* Bp = Wot + (size_t)(c0 + li) * 256 + 8 * H;
  f16v acc = {};
#pragma unroll
  for (int kc = 0; kc < 16; ++kc) {
    s8v bf = *(const s8v*)(Bp + 16 * kc);
    s8v ah = *(const s8v*)(Ah + 16 * kc);
    s8v al = *(const s8v*)(Al + 16 * kc);
    acc = __builtin_amdgcn_mfma_f32_32x32x16_bf16(ah, bf, acc, 0, 0, 0);
    acc = __builtin_amdgcn_mfma_f32_32x32x16_bf16(al, bf, acc, 0, 0, 0);
  }
  float bias = bo[c0 + li];
#pragma unroll
  for (int r = 0; r < 16; ++r) {
    int crow = (r & 3) + 8 * (r >> 2) + 4 * H;
    out[(size_t)(m0 + crow) * 256 + c0 + li] = acc[r] + bias;
  }
}

// ============================================================================
extern "C" void kernel_launch(void* const* d_in, const int* in_sizes, int n_in,
                              void* d_out, int out_size, void* d_ws, size_t ws_size,
                              hipStream_t stream) {
  const float* x    = (const float*)d_in[0];
  // d_in[1] = deep_semantics: unused by the reference
  const float* pos  = (const float*)d_in[2];
  const float* Wq   = (const float*)d_in[3];
  const float* Wk   = (const float*)d_in[4];
  const float* Wv   = (const float*)d_in[5];
  const float* Wo   = (const float*)d_in[6];
  const float* bo   = (const float*)d_in[7];
  const float* Wp1  = (const float*)d_in[8];
  const float* bp1  = (const float*)d_in[9];
  const float* Wp2  = (const float*)d_in[10];
  const float* bp2  = (const float*)d_in[11];
  const float* Wh   = (const float*)d_in[12];
  // d_in[13] = bh: cancels in softmax over keys
  const float* gate = (const float*)d_in[14];
  float* out = (float*)d_out;

  char* base = (char*)d_ws;
  short* Qb   = (short*)(base);                               // 2MB
  short* Kb   = (short*)(base + (2u << 20));                  // 2MB
  short* Vtb  = (short*)(base + (4u << 20));                  // 2MB [bh][d][n]
  short* OHhi = (short*)(base + (6u << 20));                  // 2MB
  short* OHlo = (short*)(base + (8u << 20));                  // 2MB
  short* Wt   = (short*)(base + (10u << 20));                 // 384KB
  short* Wot  = (short*)(base + (10u << 20) + (384u << 10));  // 128KB
  float* Ww   = (float*)(base + (10u << 20) + (512u << 10));  // 128KB

  k_prep<<<96,   256, 0, stream>>>(Wq, Wk, Wv, Wo, pos, Wp1, bp1, Wp2, bp2, Wh,
                                   Wt, Wot, Ww);
  k_qkv <<<768,  256, 0, stream>>>(x, Wt, Qb, Kb, Vtb);
  k_attn<<<1024, 256, 0, stream>>>(Qb, Kb, Vtb, Ww, gate, OHhi, OHlo);
  k_out <<<256,  256, 0, stream>>>(OHhi, OHlo, Wot, bo, out);
}

// Round 4
// 57.682 us; speedup vs baseline: 1.2117x; 1.2117x over previous
//
#include <hip/hip_runtime.h>
#include <hip/hip_bf16.h>

// ============================================================================
// Exact algebra (verified rounds 1-3): pos branch is rank-1 in the query index
// => pos_attn rows identical = w[b,h,j] = softmax_j(-s[b,h,j]); renorm no-op.
// out_head = (1-g)*softmax(QK^T/sqrt(dh))@V + g*(w@V).
// bf16 MFMA 32x32x16; C/D: col=lane&31, row=(reg&3)+8*(reg>>2)+4*(lane>>5).
// No-max softmax: Wq pre-scaled to exp2 units, sigma(S)~1.44 => exp2 safe.
// Round 4: undo the two bad fusions of round 3 (pv recompute in attn; f32 x
// in qkv) without adding launches: x-cvt joins k_prep's grid, pv joins
// k_qkv's V-epilogue (f32 acc in registers + atomicAdd).
// ============================================================================

constexpr int N_ = 1024, PD_ = 16;

typedef short  s8v  __attribute__((ext_vector_type(8)));
typedef float  f16v __attribute__((ext_vector_type(16)));
typedef unsigned u4v __attribute__((ext_vector_type(4)));

__device__ inline unsigned pkbf(float lo, float hi) {
  unsigned r;
  asm("v_cvt_pk_bf16_f32 %0, %1, %2" : "=v"(r) : "v"(lo), "v"(hi));
  return r;
}
__device__ inline short bf16r(float f) {
  unsigned u = __float_as_uint(f);
  u += 0x7fff + ((u >> 16) & 1);
  return (short)(u >> 16);
}
__device__ inline float bfu(short s) {
  return __uint_as_float(((unsigned)(unsigned short)s) << 16);
}

// ---- K1: W^T->bf16 (64 blk) | pos MLP+softmax + pv zero (32 blk) |
//          x->bf16 (512 blk) --------------------------------------------------
__global__ __launch_bounds__(256) void k_prep(
    const float* __restrict__ Wq, const float* __restrict__ Wk,
    const float* __restrict__ Wv, const float* __restrict__ Wo,
    const float* __restrict__ pos, const float* __restrict__ Wp1,
    const float* __restrict__ bp1, const float* __restrict__ Wp2,
    const float* __restrict__ bp2, const float* __restrict__ Wh,
    const float* __restrict__ x,
    short* __restrict__ Wt, short* __restrict__ Wot, float* __restrict__ Ww,
    short* __restrict__ xb, float* __restrict__ pv)
{
  int bid = blockIdx.x;
  int tid = threadIdx.x;

  if (bid >= 96) {
    // ---- x -> bf16, 8 elements/thread ----
    size_t idx = ((size_t)(bid - 96) * 256 + tid) * 8;
    const float4* p = (const float4*)(x + idx);
    float4 f0 = p[0], f1 = p[1];
    u4v o = { pkbf(f0.x, f0.y), pkbf(f0.z, f0.w), pkbf(f1.x, f1.y), pkbf(f1.z, f1.w) };
    *(u4v*)(xb + idx) = o;
    return;
  }

  if (bid < 64) {
    // ---- W transpose + bf16 (Wq pre-scaled by log2(e)/sqrt(32)) ----
    __shared__ float tile[64][65];
    int mat = bid >> 4, t = bid & 15;
    int k0 = (t >> 2) * 64, c0 = (t & 3) * 64;
    const float* W = mat == 0 ? Wq : mat == 1 ? Wk : mat == 2 ? Wv : Wo;
    float scale = (mat == 0) ? 0.2550348662f : 1.0f;
#pragma unroll
    for (int i = 0; i < 16; ++i) {
      int e = tid + i * 256;
      int kr = e >> 6, cc = e & 63;
      tile[kr][cc] = W[(size_t)(k0 + kr) * 256 + c0 + cc];
    }
    __syncthreads();
    short* dst = (mat == 3) ? Wot : (Wt + mat * 65536);
#pragma unroll
    for (int i = 0; i < 16; ++i) {
      int e = tid + i * 256;
      int cr = e >> 6, kk = e & 63;
      dst[(size_t)(c0 + cr) * 256 + k0 + kk] = bf16r(tile[kk][cr] * scale);
    }
    return;
  }

  // ---- pos branch: one block per (b,h); thread handles 4 n's ----
  __shared__ float sWp1[256], sbp1[16], sWp2[512], sbp2[32], sWhc[32];
  __shared__ float redm[4], reds[4];
  int bh = bid - 64;
  int b = bh >> 3, h = bh & 7;
  if (tid < 32) pv[bh * 32 + tid] = 0.0f;   // zero pv for k_qkv's atomics
  sWp1[tid] = Wp1[tid];
  sWp2[tid] = Wp2[tid];
  sWp2[tid + 256] = Wp2[tid + 256];
  if (tid < 16) sbp1[tid] = bp1[tid];
  if (tid < 32) { sbp2[tid] = bp2[tid]; sWhc[tid] = Wh[tid * 8 + h]; }
  __syncthreads();

  float a[4];
#pragma unroll
  for (int nn = 0; nn < 4; ++nn) {
    int n = nn * 256 + tid;
    const float* prow = pos + (size_t)((b << 10) + n) * PD_;
    float pr[16];
#pragma unroll
    for (int r = 0; r < 16; ++r) pr[r] = prow[r];
    float h1[16];
#pragma unroll
    for (int c = 0; c < 16; ++c) {
      float v = sbp1[c];
#pragma unroll
      for (int r = 0; r < 16; ++r) v = fmaf(pr[r], sWp1[r * 16 + c], v);
      h1[c] = fmaxf(v, 0.0f);
    }
    float s = 0.0f;
#pragma unroll
    for (int d = 0; d < 32; ++d) {
      float v = sbp2[d];
#pragma unroll
      for (int c = 0; c < 16; ++c) v = fmaf(h1[c], sWp2[c * 32 + d], v);
      s = fmaf(v, sWhc[d], s);
    }
    a[nn] = -s;   // bh[h] constant over n: cancels
  }
  float m = fmaxf(fmaxf(a[0], a[1]), fmaxf(a[2], a[3]));
#pragma unroll
  for (int off = 32; off >= 1; off >>= 1) m = fmaxf(m, __shfl_xor(m, off));
  if ((tid & 63) == 0) redm[tid >> 6] = m;
  __syncthreads();
  float M = fmaxf(fmaxf(redm[0], redm[1]), fmaxf(redm[2], redm[3]));
  float e0 = __expf(a[0] - M), e1 = __expf(a[1] - M);
  float e2 = __expf(a[2] - M), e3 = __expf(a[3] - M);
  float su = e0 + e1 + e2 + e3;
#pragma unroll
  for (int off = 32; off >= 1; off >>= 1) su += __shfl_xor(su, off);
  if ((tid & 63) == 0) reds[tid >> 6] = su;
  __syncthreads();
  float inv = 1.0f / (reds[0] + reds[1] + reds[2] + reds[3]);
  float* wr = Ww + (size_t)bh * N_;
  wr[tid]        = e0 * inv;
  wr[tid + 256]  = e1 * inv;
  wr[tid + 512]  = e2 * inv;
  wr[tid + 768]  = e3 * inv;
}

// ---- K2: QKV GEMM (bf16 x bf16), 32x32/wave; V-epilogue also accumulates
//          pv[bh][d] = sum_n w[n] V[n][d] via f32 atomics ---------------------
__global__ __launch_bounds__(256) void k_qkv(
    const short* __restrict__ xb, const short* __restrict__ Wt,
    const float* __restrict__ Ww,
    short* __restrict__ Qb, short* __restrict__ Kb, short* __restrict__ Vtb,
    float* __restrict__ pv)
{
  int tid = threadIdx.x;
  int w = tid >> 6, l = tid & 63, H = l >> 5, li = l & 31;
  int bid = blockIdx.x;
  int cb = bid % 12, mb = bid / 12;
  int m0 = mb * 64 + (w & 1) * 32;
  int c0 = cb * 64 + (w >> 1) * 32;
  const short* Ap = xb + (size_t)(m0 + li) * 256 + 8 * H;
  const short* Bp = Wt + (size_t)(c0 + li) * 256 + 8 * H;
  f16v acc = {};
#pragma unroll
  for (int kc = 0; kc < 16; ++kc) {
    s8v af = *(const s8v*)(Ap + 16 * kc);
    s8v bf = *(const s8v*)(Bp + 16 * kc);
    acc = __builtin_amdgcn_mfma_f32_32x32x16_bf16(af, bf, acc, 0, 0, 0);
  }
  int mat = c0 >> 8, mc = c0 & 255;
  int h = mc >> 5;
  int b = m0 >> 10, nb = m0 & 1023;
  int bh = b * 8 + h;
  if (mat < 2) {
    short* Dst = (mat == 0) ? Qb : Kb;
#pragma unroll
    for (int r = 0; r < 16; ++r) {
      int crow = (r & 3) + 8 * (r >> 2) + 4 * H;
      Dst[((size_t)(bh * 1024 + nb + crow)) * 32 + li] = bf16r(acc[r]);
    }
  } else {
#pragma unroll
    for (int q2 = 0; q2 < 4; ++q2) {
      uint2 val = make_uint2(pkbf(acc[q2 * 4 + 0], acc[q2 * 4 + 1]),
                             pkbf(acc[q2 * 4 + 2], acc[q2 * 4 + 3]));
      *(uint2*)(Vtb + ((size_t)(bh * 32 + li)) * 1024 + nb + 8 * q2 + 4 * H) = val;
    }
    // pv partial from the f32 accumulators already in registers
    const float* wp = Ww + (size_t)bh * N_ + nb;
    float part = 0.0f;
#pragma unroll
    for (int r = 0; r < 16; ++r) {
      int crow = (r & 3) + 8 * (r >> 2) + 4 * H;
      part = fmaf(wp[crow], acc[r], part);
    }
    atomicAdd(&pv[bh * 32 + li], part);
  }
}

// ---- K3: flash attn (no-max exp2), split-bf16 OH ----------------------------
__global__ __launch_bounds__(256) void k_attn(
    const short* __restrict__ Qb, const short* __restrict__ Kb,
    const short* __restrict__ Vtb, const float* __restrict__ pv,
    const float* __restrict__ gate,
    short* __restrict__ OHhi, short* __restrict__ OHlo)
{
  __shared__ float sml[4][32];
  __shared__ float sO[4][32][33];
  int tid = threadIdx.x;
  int w = tid >> 6, l = tid & 63, H = l >> 5, li = l & 31;
  int bid = blockIdx.x;
  int bh = (bid & 7) * 4 + (bid >> 8);   // 4 bh per XCD -> K/V L2-resident
  int qb = (bid >> 3) & 31;
  int n0 = qb * 32;

  const short* Qp = Qb + ((size_t)(bh * 1024 + n0 + li)) * 32 + 8 * H;
  s8v qf0 = *(const s8v*)(Qp);
  s8v qf1 = *(const s8v*)(Qp + 16);
  const short* Kbase = Kb + ((size_t)(bh * 1024)) * 32 + 8 * H;
  const short* Vbase = Vtb + ((size_t)(bh * 32 + li)) * 1024 + 8 * H;

  f16v acc = {};
  float lsum = 0.0f;

#pragma unroll 2
  for (int ch = 0; ch < 8; ++ch) {
    int jb = w * 256 + ch * 32;
    const short* Kp = Kbase + (size_t)(jb + li) * 32;
    s8v kf0 = *(const s8v*)(Kp);
    s8v kf1 = *(const s8v*)(Kp + 16);
    const short* Vp = Vbase + jb;
    s8v vf0 = *(const s8v*)(Vp);
    s8v vf1 = *(const s8v*)(Vp + 16);

    f16v S = {};
    S = __builtin_amdgcn_mfma_f32_32x32x16_bf16(kf0, qf0, S, 0, 0, 0);
    S = __builtin_amdgcn_mfma_f32_32x32x16_bf16(kf1, qf1, S, 0, 0, 0);

    float p[16];
#pragma unroll
    for (int r = 0; r < 16; ++r) {
      p[r] = __builtin_amdgcn_exp2f(S[r]);   // no max: sigma(S)~1.44, safe
      lsum += p[r];
    }

    unsigned a0 = pkbf(p[0], p[1]),  a1 = pkbf(p[2], p[3]);
    unsigned b0 = pkbf(p[4], p[5]),  b1 = pkbf(p[6], p[7]);
    unsigned c0 = pkbf(p[8], p[9]),  c1 = pkbf(p[10], p[11]);
    unsigned d0 = pkbf(p[12], p[13]), d1 = pkbf(p[14], p[15]);
    unsigned sa0 = __shfl_xor(a0, 32), sa1 = __shfl_xor(a1, 32);
    unsigned sb0 = __shfl_xor(b0, 32), sb1 = __shfl_xor(b1, 32);
    unsigned sc0 = __shfl_xor(c0, 32), sc1 = __shfl_xor(c1, 32);
    unsigned sd0 = __shfl_xor(d0, 32), sd1 = __shfl_xor(d1, 32);
    u4v t0 = { H ? sb0 : a0, H ? sb1 : a1, H ? b0 : sa0, H ? b1 : sa1 };
    u4v t1 = { H ? sd0 : c0, H ? sd1 : c1, H ? d0 : sc0, H ? d1 : sc1 };

    acc = __builtin_amdgcn_mfma_f32_32x32x16_bf16(vf0, __builtin_bit_cast(s8v, t0), acc, 0, 0, 0);
    acc = __builtin_amdgcn_mfma_f32_32x32x16_bf16(vf1, __builtin_bit_cast(s8v, t1), acc, 0, 0, 0);
  }

  lsum += __shfl_xor(lsum, 32);
  if (H == 0) sml[w][li] = lsum;
#pragma unroll
  for (int r = 0; r < 16; ++r) {
    int d = (r & 3) + 8 * (r >> 2) + 4 * H;
    sO[w][d][li] = acc[r];
  }
  __syncthreads();

  // combine 4 wave-partials + gate + pv, write split-bf16 OH
  int i = tid >> 3, dq = (tid & 7) * 4;
  float L = sml[0][i] + sml[1][i] + sml[2][i] + sml[3][i];
  int b = bh >> 3, h = bh & 7;
  float gh = 1.0f / (1.0f + __expf(-gate[h]));
  float invL = (1.0f - gh) / L;
  const float4 pvv = *(const float4*)(pv + bh * 32 + dq);
  float o[4] = {
    (sO[0][dq + 0][i] + sO[1][dq + 0][i] + sO[2][dq + 0][i] + sO[3][dq + 0][i]) * invL + gh * pvv.x,
    (sO[0][dq + 1][i] + sO[1][dq + 1][i] + sO[2][dq + 1][i] + sO[3][dq + 1][i]) * invL + gh * pvv.y,
    (sO[0][dq + 2][i] + sO[1][dq + 2][i] + sO[2][dq + 2][i] + sO[3][dq + 2][i]) * invL + gh * pvv.z,
    (sO[0][dq + 3][i] + sO[1][dq + 3][i] + sO[2][dq + 3][i] + sO[3][dq + 3][i]) * invL + gh * pvv.w
  };
  float hi[4], lo[4];
#pragma unroll
  for (int q = 0; q < 4; ++q) {
    hi[q] = bfu(bf16r(o[q]));
    lo[q] = o[q] - hi[q];
  }
  size_t off = ((size_t)(b * 1024 + n0 + i)) * 256 + h * 32 + dq;
  *(uint2*)(OHhi + off) = make_uint2(pkbf(hi[0], hi[1]), pkbf(hi[2], hi[3]));
  *(uint2*)(OHlo + off) = make_uint2(pkbf(lo[0], lo[1]), pkbf(lo[2], lo[3]));
}

// ---- K4: out = (OHhi+OHlo) @ Wo + bo ----------------------------------------
__global__ __launch_bounds__(256) void k_out(
    const short* __restrict__ OHhi, const short* __restrict__ OHlo,
    const short* __restrict__ Wot, const float* __restrict__ bo,
    float* __restrict__ out)
{
  int tid = threadIdx.x;
  int w = tid >> 6, l = tid & 63, H = l >> 5, li = l & 31;
  int bid = blockIdx.x;
  int m0 = (bid >> 2) * 64 + (w & 1) * 32;
  int c0 = (bid & 3) * 64 + (w >> 1) * 32;
  const short* Ah = OHhi + (size_t)(m0 + li) * 256 + 8 * H;
  const short* Al = OHlo + (size_t)(m0 + li) * 256 + 8 * H;
  const short* Bp = Wot + (size_t)(c0 + li) * 256 + 8 * H;
  f16v acc = {};
#pragma unroll
  for (int kc = 0; kc < 16; ++kc) {
    s8v bf = *(const s8v*)(Bp + 16 * kc);
    s8v ah = *(const s8v*)(Ah + 16 * kc);
    s8v al = *(const s8v*)(Al + 16 * kc);
    acc = __builtin_amdgcn_mfma_f32_32x32x16_bf16(ah, bf, acc, 0, 0, 0);
    acc = __builtin_amdgcn_mfma_f32_32x32x16_bf16(al, bf, acc, 0, 0, 0);
  }
  float bias = bo[c0 + li];
#pragma unroll
  for (int r = 0; r < 16; ++r) {
    int crow = (r & 3) + 8 * (r >> 2) + 4 * H;
    out[(size_t)(m0 + crow) * 256 + c0 + li] = acc[r] + bias;
  }
}

// ============================================================================
extern "C" void kernel_launch(void* const* d_in, const int* in_sizes, int n_in,
                              void* d_out, int out_size, void* d_ws, size_t ws_size,
                              hipStream_t stream) {
  const float* x    = (const float*)d_in[0];
  // d_in[1] = deep_semantics: unused by the reference
  const float* pos  = (const float*)d_in[2];
  const float* Wq   = (const float*)d_in[3];
  const float* Wk   = (const float*)d_in[4];
  const float* Wv   = (const float*)d_in[5];
  const float* Wo   = (const float*)d_in[6];
  const float* bo   = (const float*)d_in[7];
  const float* Wp1  = (const float*)d_in[8];
  const float* bp1  = (const float*)d_in[9];
  const float* Wp2  = (const float*)d_in[10];
  const float* bp2  = (const float*)d_in[11];
  const float* Wh   = (const float*)d_in[12];
  // d_in[13] = bh: cancels in softmax over keys
  const float* gate = (const float*)d_in[14];
  float* out = (float*)d_out;

  char* base = (char*)d_ws;
  short* Qb   = (short*)(base);                               // 2MB
  short* Kb   = (short*)(base + (2u << 20));                  // 2MB
  short* Vtb  = (short*)(base + (4u << 20));                  // 2MB [bh][d][n]
  short* OHhi = (short*)(base + (6u << 20));                  // 2MB
  short* OHlo = (short*)(base + (8u << 20));                  // 2MB
  short* xb   = (short*)(base + (10u << 20));                 // 2MB
  short* Wt   = (short*)(base + (12u << 20));                 // 384KB
  short* Wot  = (short*)(base + (12u << 20) + (384u << 10));  // 128KB
  float* Ww   = (float*)(base + (12u << 20) + (512u << 10));  // 128KB
  float* pv   = (float*)(base + (12u << 20) + (640u << 10));  // 4KB

  k_prep<<<608,  256, 0, stream>>>(Wq, Wk, Wv, Wo, pos, Wp1, bp1, Wp2, bp2, Wh,
                                   x, Wt, Wot, Ww, xb, pv);
  k_qkv <<<768,  256, 0, stream>>>(xb, Wt, Ww, Qb, Kb, Vtb, pv);
  k_attn<<<1024, 256, 0, stream>>>(Qb, Kb, Vtb, pv, gate, OHhi, OHlo);
  k_out <<<256,  256, 0, stream>>>(OHhi, OHlo, Wot, bo, out);
}

// Round 6
// 57.620 us; speedup vs baseline: 1.2130x; 1.0011x over previous
//
#include <hip/hip_runtime.h>
#include <hip/hip_cooperative_groups.h>
#include <hip/hip_bf16.h>

namespace cg = cooperative_groups;

// ============================================================================
// Exact algebra (verified rounds 1-4): pos branch is rank-1 in the query index
// => pos_attn rows identical = w[b,h,j] = softmax_j(-s[b,h,j]); renorm no-op.
// out_head = (1-g)*softmax(QK^T/sqrt(dh))@V + g*(w@V).
// bf16 MFMA 32x32x16; C/D: col=lane&31, row=(reg&3)+8*(reg>>2)+4*(lane>>5).
// No-max softmax: Wq pre-scaled to exp2 units, sigma(S)~1.44 => exp2 safe.
// Round 6: cooperative megakernel at a GUARANTEED-RESIDENT grid (512 blocks,
// launch_bounds(256,2) => 2 blocks/CU needs only <=256 VGPR). Round 5's 1024
// blocks needed 4 blocks/CU (<=128 VGPR) -> launch refused -> zeros.
// Occupancy-checked fallback to the 4-kernel path (round-4, known-good).
// ============================================================================

constexpr int N_ = 1024, PD_ = 16;

typedef short  s8v  __attribute__((ext_vector_type(8)));
typedef float  f16v __attribute__((ext_vector_type(16)));
typedef unsigned u4v __attribute__((ext_vector_type(4)));

__device__ inline unsigned pkbf(float lo, float hi) {
  unsigned r;
  asm("v_cvt_pk_bf16_f32 %0, %1, %2" : "=v"(r) : "v"(lo), "v"(hi));
  return r;
}
__device__ inline short bf16r(float f) {
  unsigned u = __float_as_uint(f);
  u += 0x7fff + ((u >> 16) & 1);
  return (short)(u >> 16);
}
__device__ inline float bfu(short s) {
  return __uint_as_float(((unsigned)(unsigned short)s) << 16);
}

union SMem {
  float tile[64][65];
  struct {
    float sWp1[256], sbp1[16], sWp2[512], sbp2[32], sWhc[32], redm[4], reds[4];
  } pos;
  struct {
    float sml[4][32];
    float sO[4][32][33];
  } attn;
};

// ---------------- phase 0: W^T->bf16 | pos MLP+softmax | x->bf16 ------------
__device__ __forceinline__ void do_prep(
    int u, int tid, SMem& sm,
    const float* __restrict__ x, const float* __restrict__ pos,
    const float* __restrict__ Wq, const float* __restrict__ Wk,
    const float* __restrict__ Wv, const float* __restrict__ Wo,
    const float* __restrict__ Wp1, const float* __restrict__ bp1,
    const float* __restrict__ Wp2, const float* __restrict__ bp2,
    const float* __restrict__ Wh,
    short* __restrict__ Wt, short* __restrict__ Wot,
    float* __restrict__ Ww, short* __restrict__ xb, float* __restrict__ pv)
{
  if (u >= 96) {
    // ---- x -> bf16, 8 elements/thread ----
    size_t idx = ((size_t)(u - 96) * 256 + tid) * 8;
    const float4* p = (const float4*)(x + idx);
    float4 f0 = p[0], f1 = p[1];
    u4v o = { pkbf(f0.x, f0.y), pkbf(f0.z, f0.w), pkbf(f1.x, f1.y), pkbf(f1.z, f1.w) };
    *(u4v*)(xb + idx) = o;
    return;
  }
  if (u < 64) {
    // ---- W transpose + bf16 (Wq pre-scaled by log2(e)/sqrt(32)) ----
    int mat = u >> 4, t = u & 15;
    int k0 = (t >> 2) * 64, c0 = (t & 3) * 64;
    const float* W = mat == 0 ? Wq : mat == 1 ? Wk : mat == 2 ? Wv : Wo;
    float scale = (mat == 0) ? 0.2550348662f : 1.0f;
#pragma unroll
    for (int i = 0; i < 16; ++i) {
      int e = tid + i * 256;
      int kr = e >> 6, cc = e & 63;
      sm.tile[kr][cc] = W[(size_t)(k0 + kr) * 256 + c0 + cc];
    }
    __syncthreads();
    short* dst = (mat == 3) ? Wot : (Wt + mat * 65536);
#pragma unroll
    for (int i = 0; i < 16; ++i) {
      int e = tid + i * 256;
      int cr = e >> 6, kk = e & 63;
      dst[(size_t)(c0 + cr) * 256 + k0 + kk] = bf16r(sm.tile[kk][cr] * scale);
    }
    return;
  }
  // ---- pos branch: one unit per (b,h); thread handles 4 n's ----
  int bh = u - 64;
  int b = bh >> 3, h = bh & 7;
  if (tid < 32) pv[bh * 32 + tid] = 0.0f;   // zero pv for phase-1 atomics
  sm.pos.sWp1[tid] = Wp1[tid];
  sm.pos.sWp2[tid] = Wp2[tid];
  sm.pos.sWp2[tid + 256] = Wp2[tid + 256];
  if (tid < 16) sm.pos.sbp1[tid] = bp1[tid];
  if (tid < 32) { sm.pos.sbp2[tid] = bp2[tid]; sm.pos.sWhc[tid] = Wh[tid * 8 + h]; }
  __syncthreads();

  float a[4];
#pragma unroll
  for (int nn = 0; nn < 4; ++nn) {
    int n = nn * 256 + tid;
    const float* prow = pos + (size_t)((b << 10) + n) * PD_;
    float pr[16];
#pragma unroll
    for (int r = 0; r < 16; ++r) pr[r] = prow[r];
    float h1[16];
#pragma unroll
    for (int c = 0; c < 16; ++c) {
      float v = sm.pos.sbp1[c];
#pragma unroll
      for (int r = 0; r < 16; ++r) v = fmaf(pr[r], sm.pos.sWp1[r * 16 + c], v);
      h1[c] = fmaxf(v, 0.0f);
    }
    float s = 0.0f;
#pragma unroll
    for (int d = 0; d < 32; ++d) {
      float v = sm.pos.sbp2[d];
#pragma unroll
      for (int c = 0; c < 16; ++c) v = fmaf(h1[c], sm.pos.sWp2[c * 32 + d], v);
      s = fmaf(v, sm.pos.sWhc[d], s);
    }
    a[nn] = -s;   // bh[h] constant over n: cancels
  }
  float m = fmaxf(fmaxf(a[0], a[1]), fmaxf(a[2], a[3]));
#pragma unroll
  for (int off = 32; off >= 1; off >>= 1) m = fmaxf(m, __shfl_xor(m, off));
  if ((tid & 63) == 0) sm.pos.redm[tid >> 6] = m;
  __syncthreads();
  float M = fmaxf(fmaxf(sm.pos.redm[0], sm.pos.redm[1]),
                  fmaxf(sm.pos.redm[2], sm.pos.redm[3]));
  float e0 = __expf(a[0] - M), e1 = __expf(a[1] - M);
  float e2 = __expf(a[2] - M), e3 = __expf(a[3] - M);
  float su = e0 + e1 + e2 + e3;
#pragma unroll
  for (int off = 32; off >= 1; off >>= 1) su += __shfl_xor(su, off);
  if ((tid & 63) == 0) sm.pos.reds[tid >> 6] = su;
  __syncthreads();
  float inv = 1.0f / (sm.pos.reds[0] + sm.pos.reds[1] + sm.pos.reds[2] + sm.pos.reds[3]);
  float* wr = Ww + (size_t)bh * N_;
  wr[tid]        = e0 * inv;
  wr[tid + 256]  = e1 * inv;
  wr[tid + 512]  = e2 * inv;
  wr[tid + 768]  = e3 * inv;
}

// ---------------- phase 1: QKV GEMM + pv atomics ----------------------------
__device__ __forceinline__ void do_qkv(
    int u, int tid,
    const short* __restrict__ xb, const short* __restrict__ Wt,
    const float* __restrict__ Ww,
    short* __restrict__ Qb, short* __restrict__ Kb, short* __restrict__ Vtb,
    float* __restrict__ pv)
{
  int w = tid >> 6, l = tid & 63, H = l >> 5, li = l & 31;
  int cb = u % 12, mb = u / 12;
  int m0 = mb * 64 + (w & 1) * 32;
  int c0 = cb * 64 + (w >> 1) * 32;
  const short* Ap = xb + (size_t)(m0 + li) * 256 + 8 * H;
  const short* Bp = Wt + (size_t)(c0 + li) * 256 + 8 * H;
  f16v acc = {};
#pragma unroll
  for (int kc = 0; kc < 16; ++kc) {
    s8v af = *(const s8v*)(Ap + 16 * kc);
    s8v bf = *(const s8v*)(Bp + 16 * kc);
    acc = __builtin_amdgcn_mfma_f32_32x32x16_bf16(af, bf, acc, 0, 0, 0);
  }
  int mat = c0 >> 8, mc = c0 & 255;
  int h = mc >> 5;
  int b = m0 >> 10, nb = m0 & 1023;
  int bh = b * 8 + h;
  if (mat < 2) {
    short* Dst = (mat == 0) ? Qb : Kb;
#pragma unroll
    for (int r = 0; r < 16; ++r) {
      int crow = (r & 3) + 8 * (r >> 2) + 4 * H;
      Dst[((size_t)(bh * 1024 + nb + crow)) * 32 + li] = bf16r(acc[r]);
    }
  } else {
#pragma unroll
    for (int q2 = 0; q2 < 4; ++q2) {
      uint2 val = make_uint2(pkbf(acc[q2 * 4 + 0], acc[q2 * 4 + 1]),
                             pkbf(acc[q2 * 4 + 2], acc[q2 * 4 + 3]));
      *(uint2*)(Vtb + ((size_t)(bh * 32 + li)) * 1024 + nb + 8 * q2 + 4 * H) = val;
    }
    const float* wp = Ww + (size_t)bh * N_ + nb;
    float part = 0.0f;
#pragma unroll
    for (int r = 0; r < 16; ++r) {
      int crow = (r & 3) + 8 * (r >> 2) + 4 * H;
      part = fmaf(wp[crow], acc[r], part);
    }
    atomicAdd(&pv[bh * 32 + li], part);
  }
}

// ---------------- phase 2: flash attn (no-max exp2) + gate + split-bf16 OH --
__device__ __forceinline__ void do_attn(
    int u, int tid, SMem& sm,
    const short* __restrict__ Qb, const short* __restrict__ Kb,
    const short* __restrict__ Vtb, const float* __restrict__ pv,
    const float* __restrict__ gate,
    short* __restrict__ OHhi, short* __restrict__ OHlo)
{
  int w = tid >> 6, l = tid & 63, H = l >> 5, li = l & 31;
  int bh = (u & 7) * 4 + (u >> 8);   // 4 bh per XCD -> K/V L2-resident
  int qb = (u >> 3) & 31;
  int n0 = qb * 32;

  const short* Qp = Qb + ((size_t)(bh * 1024 + n0 + li)) * 32 + 8 * H;
  s8v qf0 = *(const s8v*)(Qp);
  s8v qf1 = *(const s8v*)(Qp + 16);
  const short* Kbase = Kb + ((size_t)(bh * 1024)) * 32 + 8 * H;
  const short* Vbase = Vtb + ((size_t)(bh * 32 + li)) * 1024 + 8 * H;

  f16v acc = {};
  float lsum = 0.0f;

  for (int ch = 0; ch < 8; ++ch) {
    int jb = w * 256 + ch * 32;
    const short* Kp = Kbase + (size_t)(jb + li) * 32;
    s8v kf0 = *(const s8v*)(Kp);
    s8v kf1 = *(const s8v*)(Kp + 16);
    const short* Vp = Vbase + jb;
    s8v vf0 = *(const s8v*)(Vp);
    s8v vf1 = *(const s8v*)(Vp + 16);

    f16v S = {};
    S = __builtin_amdgcn_mfma_f32_32x32x16_bf16(kf0, qf0, S, 0, 0, 0);
    S = __builtin_amdgcn_mfma_f32_32x32x16_bf16(kf1, qf1, S, 0, 0, 0);

    float p[16];
#pragma unroll
    for (int r = 0; r < 16; ++r) {
      p[r] = __builtin_amdgcn_exp2f(S[r]);   // no max: sigma(S)~1.44, safe
      lsum += p[r];
    }

    unsigned a0 = pkbf(p[0], p[1]),  a1 = pkbf(p[2], p[3]);
    unsigned b0 = pkbf(p[4], p[5]),  b1 = pkbf(p[6], p[7]);
    unsigned c0 = pkbf(p[8], p[9]),  c1 = pkbf(p[10], p[11]);
    unsigned d0 = pkbf(p[12], p[13]), d1 = pkbf(p[14], p[15]);
    unsigned sa0 = __shfl_xor(a0, 32), sa1 = __shfl_xor(a1, 32);
    unsigned sb0 = __shfl_xor(b0, 32), sb1 = __shfl_xor(b1, 32);
    unsigned sc0 = __shfl_xor(c0, 32), sc1 = __shfl_xor(c1, 32);
    unsigned sd0 = __shfl_xor(d0, 32), sd1 = __shfl_xor(d1, 32);
    u4v t0 = { H ? sb0 : a0, H ? sb1 : a1, H ? b0 : sa0, H ? b1 : sa1 };
    u4v t1 = { H ? sd0 : c0, H ? sd1 : c1, H ? d0 : sc0, H ? d1 : sc1 };

    acc = __builtin_amdgcn_mfma_f32_32x32x16_bf16(vf0, __builtin_bit_cast(s8v, t0), acc, 0, 0, 0);
    acc = __builtin_amdgcn_mfma_f32_32x32x16_bf16(vf1, __builtin_bit_cast(s8v, t1), acc, 0, 0, 0);
  }

  lsum += __shfl_xor(lsum, 32);
  __syncthreads();   // protect sm reuse (prior phase / prior iteration reads)
  if (H == 0) sm.attn.sml[w][li] = lsum;
#pragma unroll
  for (int r = 0; r < 16; ++r) {
    int d = (r & 3) + 8 * (r >> 2) + 4 * H;
    sm.attn.sO[w][d][li] = acc[r];
  }
  __syncthreads();

  int i = tid >> 3, dq = (tid & 7) * 4;
  float L = sm.attn.sml[0][i] + sm.attn.sml[1][i] + sm.attn.sml[2][i] + sm.attn.sml[3][i];
  int b = bh >> 3, h = bh & 7;
  float gh = 1.0f / (1.0f + __expf(-gate[h]));
  float invL = (1.0f - gh) / L;
  const float4 pvv = *(const float4*)(pv + bh * 32 + dq);
  float o[4] = {
    (sm.attn.sO[0][dq + 0][i] + sm.attn.sO[1][dq + 0][i] + sm.attn.sO[2][dq + 0][i] + sm.attn.sO[3][dq + 0][i]) * invL + gh * pvv.x,
    (sm.attn.sO[0][dq + 1][i] + sm.attn.sO[1][dq + 1][i] + sm.attn.sO[2][dq + 1][i] + sm.attn.sO[3][dq + 1][i]) * invL + gh * pvv.y,
    (sm.attn.sO[0][dq + 2][i] + sm.attn.sO[1][dq + 2][i] + sm.attn.sO[2][dq + 2][i] + sm.attn.sO[3][dq + 2][i]) * invL + gh * pvv.z,
    (sm.attn.sO[0][dq + 3][i] + sm.attn.sO[1][dq + 3][i] + sm.attn.sO[2][dq + 3][i] + sm.attn.sO[3][dq + 3][i]) * invL + gh * pvv.w
  };
  float hi[4], lo[4];
#pragma unroll
  for (int q = 0; q < 4; ++q) {
    hi[q] = bfu(bf16r(o[q]));
    lo[q] = o[q] - hi[q];
  }
  size_t off = ((size_t)(b * 1024 + n0 + i)) * 256 + h * 32 + dq;
  *(uint2*)(OHhi + off) = make_uint2(pkbf(hi[0], hi[1]), pkbf(hi[2], hi[3]));
  *(uint2*)(OHlo + off) = make_uint2(pkbf(lo[0], lo[1]), pkbf(lo[2], lo[3]));
}

// ---------------- phase 3: out = (OHhi+OHlo) @ Wo + bo ----------------------
__device__ __forceinline__ void do_out(
    int u, int tid,
    const short* __restrict__ OHhi, const short* __restrict__ OHlo,
    const short* __restrict__ Wot, const float* __restrict__ bo,
    float* __restrict__ out)
{
  int w = tid >> 6, l = tid & 63, H = l >> 5, li = l & 31;
  int m0 = (u >> 2) * 64 + (w & 1) * 32;
  int c0 = (u & 3) * 64 + (w >> 1) * 32;
  const short* Ah = OHhi + (size_t)(m0 + li) * 256 + 8 * H;
  const short* Al = OHlo + (size_t)(m0 + li) * 256 + 8 * H;
  const short* Bp = Wot + (size_t)(c0 + li) * 256 + 8 * H;
  f16v acc = {};
#pragma unroll
  for (int kc = 0; kc < 16; ++kc) {
    s8v bf = *(const s8v*)(Bp + 16 * kc);
    s8v ah = *(const s8v*)(Ah + 16 * kc);
    s8v al = *(const s8v*)(Al + 16 * kc);
    acc = __builtin_amdgcn_mfma_f32_32x32x16_bf16(ah, bf, acc, 0, 0, 0);
    acc = __builtin_amdgcn_mfma_f32_32x32x16_bf16(al, bf, acc, 0, 0, 0);
  }
  float bias = bo[c0 + li];
#pragma unroll
  for (int r = 0; r < 16; ++r) {
    int crow = (r & 3) + 8 * (r >> 2) + 4 * H;
    out[(size_t)(m0 + crow) * 256 + c0 + li] = acc[r] + bias;
  }
}

// ---------------- fused cooperative kernel (512 blocks, 2/CU guaranteed) ----
__global__ __launch_bounds__(256, 2) void k_fused(
    const float* __restrict__ x, const float* __restrict__ pos,
    const float* __restrict__ Wq, const float* __restrict__ Wk,
    const float* __restrict__ Wv, const float* __restrict__ Wo,
    const float* __restrict__ bo, const float* __restrict__ Wp1,
    const float* __restrict__ bp1, const float* __restrict__ Wp2,
    const float* __restrict__ bp2, const float* __restrict__ Wh,
    const float* __restrict__ gate, float* __restrict__ out,
    short* __restrict__ Qb, short* __restrict__ Kb, short* __restrict__ Vtb,
    short* __restrict__ OHhi, short* __restrict__ OHlo,
    short* __restrict__ xb, short* __restrict__ Wt, short* __restrict__ Wot,
    float* __restrict__ Ww, float* __restrict__ pv)
{
  __shared__ SMem sm;
  cg::grid_group grid = cg::this_grid();
  int tid = threadIdx.x;

  for (int u = blockIdx.x; u < 608; u += gridDim.x)
    do_prep(u, tid, sm, x, pos, Wq, Wk, Wv, Wo, Wp1, bp1, Wp2, bp2, Wh,
            Wt, Wot, Ww, xb, pv);
  grid.sync();
  for (int u = blockIdx.x; u < 768; u += gridDim.x)
    do_qkv(u, tid, xb, Wt, Ww, Qb, Kb, Vtb, pv);
  grid.sync();
  for (int u = blockIdx.x; u < 1024; u += gridDim.x)
    do_attn(u, tid, sm, Qb, Kb, Vtb, pv, gate, OHhi, OHlo);
  grid.sync();
  for (int u = blockIdx.x; u < 256; u += gridDim.x)
    do_out(u, tid, OHhi, OHlo, Wot, bo, out);
}

// ---------------- fallback wrappers (round-4 path) --------------------------
__global__ __launch_bounds__(256, 2) void k_p0(
    const float* x, const float* pos, const float* Wq, const float* Wk,
    const float* Wv, const float* Wo, const float* Wp1, const float* bp1,
    const float* Wp2, const float* bp2, const float* Wh,
    short* Wt, short* Wot, float* Ww, short* xb, float* pv)
{
  __shared__ SMem sm;
  for (int u = blockIdx.x; u < 608; u += gridDim.x)
    do_prep(u, threadIdx.x, sm, x, pos, Wq, Wk, Wv, Wo, Wp1, bp1, Wp2, bp2, Wh,
            Wt, Wot, Ww, xb, pv);
}
__global__ __launch_bounds__(256, 2) void k_p1(
    const short* xb, const short* Wt, const float* Ww,
    short* Qb, short* Kb, short* Vtb, float* pv)
{
  for (int u = blockIdx.x; u < 768; u += gridDim.x)
    do_qkv(u, threadIdx.x, xb, Wt, Ww, Qb, Kb, Vtb, pv);
}
__global__ __launch_bounds__(256, 2) void k_p2(
    const short* Qb, const short* Kb, const short* Vtb, const float* pv,
    const float* gate, short* OHhi, short* OHlo)
{
  __shared__ SMem sm;
  for (int u = blockIdx.x; u < 1024; u += gridDim.x)
    do_attn(u, threadIdx.x, sm, Qb, Kb, Vtb, pv, gate, OHhi, OHlo);
}
__global__ __launch_bounds__(256, 2) void k_p3(
    const short* OHhi, const short* OHlo, const short* Wot, const float* bo,
    float* out)
{
  for (int u = blockIdx.x; u < 256; u += gridDim.x)
    do_out(u, threadIdx.x, OHhi, OHlo, Wot, bo, out);
}

// ============================================================================
extern "C" void kernel_launch(void* const* d_in, const int* in_sizes, int n_in,
                              void* d_out, int out_size, void* d_ws, size_t ws_size,
                              hipStream_t stream) {
  const float* x    = (const float*)d_in[0];
  // d_in[1] = deep_semantics: unused by the reference
  const float* pos  = (const float*)d_in[2];
  const float* Wq   = (const float*)d_in[3];
  const float* Wk   = (const float*)d_in[4];
  const float* Wv   = (const float*)d_in[5];
  const float* Wo   = (const float*)d_in[6];
  const float* bo   = (const float*)d_in[7];
  const float* Wp1  = (const float*)d_in[8];
  const float* bp1  = (const float*)d_in[9];
  const float* Wp2  = (const float*)d_in[10];
  const float* bp2  = (const float*)d_in[11];
  const float* Wh   = (const float*)d_in[12];
  // d_in[13] = bh: cancels in softmax over keys
  const float* gate = (const float*)d_in[14];
  float* out = (float*)d_out;

  char* base = (char*)d_ws;
  short* Qb   = (short*)(base);                               // 2MB
  short* Kb   = (short*)(base + (2u << 20));                  // 2MB
  short* Vtb  = (short*)(base + (4u << 20));                  // 2MB [bh][d][n]
  short* OHhi = (short*)(base + (6u << 20));                  // 2MB
  short* OHlo = (short*)(base + (8u << 20));                  // 2MB
  short* xb   = (short*)(base + (10u << 20));                 // 2MB
  short* Wt   = (short*)(base + (12u << 20));                 // 384KB
  short* Wot  = (short*)(base + (12u << 20) + (384u << 10));  // 128KB
  float* Ww   = (float*)(base + (12u << 20) + (512u << 10));  // 128KB
  float* pv   = (float*)(base + (12u << 20) + (640u << 10));  // 4KB

  // Capture-safe occupancy query: take the cooperative path only if 512
  // blocks are guaranteed co-resident (MI355X: 256 CUs).
  int maxb = 0;
  hipError_t qerr = hipOccupancyMaxActiveBlocksPerMultiprocessor(
      &maxb, (const void*)k_fused, 256, 0);
  bool coop_ok = (qerr == hipSuccess) && (maxb * 256 >= 512);

  if (coop_ok) {
    void* args[] = {
      (void*)&x, (void*)&pos, (void*)&Wq, (void*)&Wk, (void*)&Wv, (void*)&Wo,
      (void*)&bo, (void*)&Wp1, (void*)&bp1, (void*)&Wp2, (void*)&bp2, (void*)&Wh,
      (void*)&gate, (void*)&out, (void*)&Qb, (void*)&Kb, (void*)&Vtb,
      (void*)&OHhi, (void*)&OHlo, (void*)&xb, (void*)&Wt, (void*)&Wot,
      (void*)&Ww, (void*)&pv
    };
    hipError_t lerr = hipLaunchCooperativeKernel((void*)k_fused, dim3(512),
                                                 dim3(256), args, 0, stream);
    if (lerr == hipSuccess) return;
  }

  // Fallback: 4-kernel path (round-4 structure, known-good).
  k_p0<<<608,  256, 0, stream>>>(x, pos, Wq, Wk, Wv, Wo, Wp1, bp1, Wp2, bp2, Wh,
                                 Wt, Wot, Ww, xb, pv);
  k_p1<<<768,  256, 0, stream>>>(xb, Wt, Ww, Qb, Kb, Vtb, pv);
  k_p2<<<1024, 256, 0, stream>>>(Qb, Kb, Vtb, pv, gate, OHhi, OHlo);
  k_p3<<<256,  256, 0, stream>>>(OHhi, OHlo, Wot, bo, out);
}